// Round 1
// baseline (12191.879 us; speedup 1.0000x reference)
//
#include <hip/hip_runtime.h>
#include <cstddef>

// FDRNN: fuzzy membership -> FC(200->1024->1024->1024->128) -> 2-layer tanh RNN (H=512)
// B=64, S=512 -> 32768 rows. All fp32 (correctness-first baseline).
//
// ws layout (floats):
//   pre : 16,777,216   [32768 x 512]  RNN pre-activations (reused for layer 0 and 1)
//   t0  :  4,194,304   [4096 x 1024]  FC ping
//   t1  :  4,194,304   [4096 x 1024]  FC pong
//   zc  :    819,200   [4096 x 200]   fuzzy chunk
//   f3  :    524,288   [4096 x 128]   fc3 chunk
//   WT0 :    262,144   w_hh0 transposed
//   WT1 :    262,144   w_hh1 transposed
// total ~27.0M floats = 108 MB. h0 sequence is staged in d_out (overwritten by layer 1).

__global__ void fuzzy_kernel(const float* __restrict__ x, const float* __restrict__ fp,
                             float* __restrict__ z, int nrows) {
  int idx = blockIdx.x * blockDim.x + threadIdx.x;
  int total = nrows * 200;
  if (idx >= total) return;
  int r = idx / 200;
  int f = idx - r * 200;       // f = k*50 + i
  int i = f % 50;
  float xv = x[r * 50 + i];
  float mu = fp[2 * f];
  float sg = fp[2 * f + 1];
  float d = xv - mu;
  z[idx] = expf(-(d * d) / sg);
}

// C[M,N] = A[M,K] @ W[N,K]^T + b1 (+ b2). Requires M%128==0, N%128==0, K%8==0.
__global__ __launch_bounds__(256) void gemm_bias(
    const float* __restrict__ A, const float* __restrict__ W,
    const float* __restrict__ b1, const float* __restrict__ b2,
    float* __restrict__ C, int M, int N, int K) {
  __shared__ float As[8][128];
  __shared__ float Bs[8][128];
  int tid = threadIdx.x;
  int bm = blockIdx.y * 128;
  int bn = blockIdx.x * 128;
  int ar = tid >> 1;           // 0..127: tile row (for staging)
  int ac = (tid & 1) * 4;      // 0 or 4: k-offset (float4)
  int ty = tid >> 4;           // 0..15
  int tx = tid & 15;           // 0..15

  float acc[8][8];
#pragma unroll
  for (int i = 0; i < 8; i++)
#pragma unroll
    for (int j = 0; j < 8; j++) acc[i][j] = 0.f;

  const float* Arow = A + (size_t)(bm + ar) * K + ac;
  const float* Wrow = W + (size_t)(bn + ar) * K + ac;

  for (int k0 = 0; k0 < K; k0 += 8) {
    float4 av = *(const float4*)(Arow + k0);
    float4 bv = *(const float4*)(Wrow + k0);
    __syncthreads();
    As[ac + 0][ar] = av.x; As[ac + 1][ar] = av.y;
    As[ac + 2][ar] = av.z; As[ac + 3][ar] = av.w;
    Bs[ac + 0][ar] = bv.x; Bs[ac + 1][ar] = bv.y;
    Bs[ac + 2][ar] = bv.z; Bs[ac + 3][ar] = bv.w;
    __syncthreads();
#pragma unroll
    for (int kk = 0; kk < 8; kk++) {
      float a0[8], bb[8];
      *(float4*)&a0[0] = *(const float4*)&As[kk][ty * 8];
      *(float4*)&a0[4] = *(const float4*)&As[kk][ty * 8 + 4];
      *(float4*)&bb[0] = *(const float4*)&Bs[kk][tx * 8];
      *(float4*)&bb[4] = *(const float4*)&Bs[kk][tx * 8 + 4];
#pragma unroll
      for (int i = 0; i < 8; i++)
#pragma unroll
        for (int j = 0; j < 8; j++)
          acc[i][j] = fmaf(a0[i], bb[j], acc[i][j]);
    }
  }

  float bj[8];
#pragma unroll
  for (int j = 0; j < 8; j++) {
    int n = bn + tx * 8 + j;
    bj[j] = b1[n] + (b2 ? b2[n] : 0.f);
  }
#pragma unroll
  for (int i = 0; i < 8; i++) {
    int row = bm + ty * 8 + i;
    float* Crow = C + (size_t)row * N + bn + tx * 8;
    float4 v0 = {acc[i][0] + bj[0], acc[i][1] + bj[1],
                 acc[i][2] + bj[2], acc[i][3] + bj[3]};
    float4 v1 = {acc[i][4] + bj[4], acc[i][5] + bj[5],
                 acc[i][6] + bj[6], acc[i][7] + bj[7]};
    *(float4*)Crow = v0;
    *(float4*)(Crow + 4) = v1;
  }
}

__global__ void transpose512(const float* __restrict__ W, float* __restrict__ WT) {
  __shared__ float tile[32][33];
  int bx = blockIdx.x * 32, by = blockIdx.y * 32;
  int tx = threadIdx.x, ty = threadIdx.y;  // block (32,8)
#pragma unroll
  for (int j = 0; j < 32; j += 8)
    tile[ty + j][tx] = W[(size_t)(by + ty + j) * 512 + bx + tx];
  __syncthreads();
#pragma unroll
  for (int j = 0; j < 32; j += 8)
    WT[(size_t)(bx + ty + j) * 512 + by + tx] = tile[tx][ty + j];
}

// One block per batch element; 512 threads = one output element each.
// h_t[o] = tanh(pre[b,t,o] + sum_j WT[j][o] * h_{t-1}[j]); WT is w_hh transposed
// so lane o's load of WT[j*512+o] is coalesced and L2-resident (1 MB).
__global__ __launch_bounds__(512) void rnn_layer_k(
    const float* __restrict__ pre, const float* __restrict__ WT,
    float* __restrict__ out) {
  int b = blockIdx.x;
  int o = threadIdx.x;
  __shared__ float h[512];
  h[o] = 0.f;
  __syncthreads();
  const float* preb = pre + (size_t)b * 512 * 512;
  float* outb = out + (size_t)b * 512 * 512;
  for (int t = 0; t < 512; t++) {
    float a0 = preb[t * 512 + o];
    float a1 = 0.f, a2 = 0.f, a3 = 0.f;
#pragma unroll 8
    for (int j = 0; j < 512; j += 4) {
      a0 = fmaf(WT[(j + 0) * 512 + o], h[j + 0], a0);
      a1 = fmaf(WT[(j + 1) * 512 + o], h[j + 1], a1);
      a2 = fmaf(WT[(j + 2) * 512 + o], h[j + 2], a2);
      a3 = fmaf(WT[(j + 3) * 512 + o], h[j + 3], a3);
    }
    float hn = tanhf((a0 + a1) + (a2 + a3));
    __syncthreads();          // all reads of h done
    h[o] = hn;
    outb[t * 512 + o] = hn;
    __syncthreads();          // h visible for next step
  }
}

extern "C" void kernel_launch(void* const* d_in, const int* in_sizes, int n_in,
                              void* d_out, int out_size, void* d_ws, size_t ws_size,
                              hipStream_t stream) {
  const float* x     = (const float*)d_in[0];
  const float* fp    = (const float*)d_in[1];
  const float* fc0_w = (const float*)d_in[2];
  const float* fc0_b = (const float*)d_in[3];
  const float* fc1_w = (const float*)d_in[4];
  const float* fc1_b = (const float*)d_in[5];
  const float* fc2_w = (const float*)d_in[6];
  const float* fc2_b = (const float*)d_in[7];
  const float* fc3_w = (const float*)d_in[8];
  const float* fc3_b = (const float*)d_in[9];
  const float* w_ih0 = (const float*)d_in[10];
  const float* w_hh0 = (const float*)d_in[11];
  const float* b_ih0 = (const float*)d_in[12];
  const float* b_hh0 = (const float*)d_in[13];
  const float* w_ih1 = (const float*)d_in[14];
  const float* w_hh1 = (const float*)d_in[15];
  const float* b_ih1 = (const float*)d_in[16];
  const float* b_hh1 = (const float*)d_in[17];
  float* out = (float*)d_out;
  float* ws  = (float*)d_ws;

  float* pre = ws;                    // 16,777,216
  float* t0  = pre + 16777216;        // 4,194,304
  float* t1  = t0 + 4194304;          // 4,194,304
  float* zc  = t1 + 4194304;          // 819,200
  float* f3  = zc + 819200;           // 524,288
  float* WT0 = f3 + 524288;           // 262,144
  float* WT1 = WT0 + 262144;          // 262,144

  transpose512<<<dim3(16, 16), dim3(32, 8), 0, stream>>>(w_hh0, WT0);
  transpose512<<<dim3(16, 16), dim3(32, 8), 0, stream>>>(w_hh1, WT1);

  const int CH = 4096;  // 32768 rows in 8 chunks
  for (int c = 0; c < 8; c++) {
    size_t row0 = (size_t)c * CH;
    fuzzy_kernel<<<(CH * 200 + 255) / 256, 256, 0, stream>>>(x + row0 * 50, fp, zc, CH);
    gemm_bias<<<dim3(8, 32), 256, 0, stream>>>(zc, fc0_w, fc0_b, nullptr, t0, CH, 1024, 200);
    gemm_bias<<<dim3(8, 32), 256, 0, stream>>>(t0, fc1_w, fc1_b, nullptr, t1, CH, 1024, 1024);
    gemm_bias<<<dim3(8, 32), 256, 0, stream>>>(t1, fc2_w, fc2_b, nullptr, t0, CH, 1024, 1024);
    gemm_bias<<<dim3(1, 32), 256, 0, stream>>>(t0, fc3_w, fc3_b, nullptr, f3, CH, 128, 1024);
    gemm_bias<<<dim3(4, 32), 256, 0, stream>>>(f3, w_ih0, b_ih0, b_hh0,
                                               pre + row0 * 512, CH, 512, 128);
  }

  // RNN layer 0: pre -> h0 (staged in d_out)
  rnn_layer_k<<<64, 512, 0, stream>>>(pre, WT0, out);
  // pre1 = h0 @ w_ih1^T + b_ih1 + b_hh1 (reuse pre buffer)
  gemm_bias<<<dim3(4, 256), 256, 0, stream>>>(out, w_ih1, b_ih1, b_hh1, pre, 32768, 512, 512);
  // RNN layer 1: pre -> final output (overwrites h0 staging)
  rnn_layer_k<<<64, 512, 0, stream>>>(pre, WT1, out);
}